// Round 6
// baseline (2482.635 us; speedup 1.0000x reference)
//
#include <hip/hip_runtime.h>

typedef __attribute__((ext_vector_type(8)))  short          bf16x8;
typedef __attribute__((ext_vector_type(4)))  short          bf16x4;
typedef __attribute__((ext_vector_type(16))) float          f32x16;
typedef __attribute__((ext_vector_type(8)))  unsigned int   u32x8;
typedef __attribute__((ext_vector_type(4)))  unsigned short ushort4v;
typedef __attribute__((ext_vector_type(4)))  float          float4v;

#define DEV static __device__ __forceinline__
#define MFMA32(A,B,C) __builtin_amdgcn_mfma_f32_32x32x16_bf16(A,B,C,0,0,0)

// ---- workspace element offsets (unsigned short elements) ----
// WRES: weight tile STREAM in exact consumption order:
//   for st in 0..6: 343 conv tiles (7 layers x 49 taps) + 1 last_w tile
//   = 2408 tiles x 4096 shorts (8KB) each, frag-major [frag(ks*2+mt)][lane][8]
#define NTILES   2408
#define WRES_OFF 0u           // 2408 * 4096                        = 9,863,168
#define FW_OFF   9863168u     // 49 taps * 2 frag * 64 lane * 8     =    50,176
#define P1_OFF   9913344u     // 256 * 2048                         =   524,288
#define P2_OFF   10437632u    // 1792 * 256 (padded rows)           =   458,752
#define ACT0_OFF 10896384u    // 1024 * 64p * 64c                   = 4,194,304
#define PV_OFF   15090688u    // 1024 * 32 * 64                     = 2,097,152
#define HID_OFF  17187840u    // 1024 * 256                         =   262,144
// total 17,449,984 ushorts = 34.9 MB

// ---- d_out offsets (floats) ----
#define VAL_OFF 1740800
#define PID_OFF 1741824

// ---- tower LDS map ----
// acts: rows of 136B (64ch*2B + 8B pad -> 2-way-max banks for b64 access)
// per image 64*136 = 8704B; double buffered, 4 images.
// EXCH: 16 slots x 4KB f32 partial-acc exchange (chunk-major, conflict-free)
#define RS       136
#define IMG_ACT  8704
#define ACT_A    0
#define ACT_B    34816
#define EXCH     69632
#define SM_Z     135168
#define SM_BYTES 135424

DEV float bf2f(unsigned short u){ union { unsigned int i; float f; } v; v.i = ((unsigned int)u) << 16; return v.f; }
DEV unsigned short f2bf(float f){
  union { float f; unsigned int i; } v; v.f = f;
  unsigned int x = v.i;
  return (unsigned short)((x + 0x7fffu + ((x >> 16) & 1u)) >> 16);  // RNE
}

// ======================= weight prep =======================
// res_w (7,7,64,64,7,7) f32 -> stream tile (L*49+t+L/7), frag-major:
// element (lane,j) of frag (ks*2+mt) = W[o = mt*32 + (lane&31)][c = ks*16 + (lane>>5)*8 + j]
__global__ void prep_res_k(const float* __restrict__ res_w, unsigned short* __restrict__ ws){
  __shared__ float buf[3136];
  int bx = blockIdx.x;             // L*64 + o
  int L = bx >> 6, o = bx & 63;
  const float* src = res_w + (size_t)bx * 3136;   // (o fixed): [c][dy][dx] contiguous
  for (int e = threadIdx.x; e < 3136; e += 256) buf[e] = src[e];
  __syncthreads();
  unsigned short* dst = ws + WRES_OFF;
  int mt = o >> 5, lrow = o & 31;
  int tilebase = L*49 + L/7;
  for (int e = threadIdx.x; e < 3136; e += 256){
    int t = e >> 6, c = e & 63;
    int ks = c >> 4, hi = (c >> 3) & 1, j = c & 7;
    int lane = hi*32 + lrow;
    dst[(size_t)(tilebase + t)*4096 + ((ks*2 + mt)*64 + lane)*8 + j] = f2bf(buf[c*49 + t]);
  }
}

// first_w -> fw[t][mt][lane][8] (K=16: c = (lane>>5)*8+j, 12 real + 4 zero)
// last_w  -> stream tile (st*344+343), frag-major
// pfc1/pfc2 cast (+pad)
__global__ void prep_misc_k(const float* __restrict__ first_w, const float* __restrict__ last_w,
                            const float* __restrict__ pfc1_w, const float* __restrict__ pfc2_w,
                            unsigned short* __restrict__ ws){
  const int n_fw = 49*1024, n_lw = 28672, n_p1 = 524288, n_p2 = 458752;
  const int total = n_fw + n_lw + n_p1 + n_p2;
  for (int d = blockIdx.x*256 + threadIdx.x; d < total; d += gridDim.x*256){
    if (d < n_fw){
      int t = d >> 10, r = d & 1023;
      int mt = r >> 9, lane = (r >> 3) & 63, j = r & 7;
      int o = mt*32 + (lane & 31);
      int c = ((lane >> 5) << 3) + j;
      float v = (o < 63 && c < 12) ? first_w[(o*12 + c)*49 + t] : 0.f;
      ws[FW_OFF + d] = f2bf(v);
    } else if (d < n_fw + n_lw){
      int e = d - n_fw;
      int st = e >> 12, r = e & 4095;
      int f = r >> 9, lane = (r >> 3) & 63, j = r & 7;
      int ks = f >> 1, mt = f & 1;
      int o = mt*32 + (lane & 31);
      int c = ks*16 + ((lane >> 5) << 3) + j;
      ws[WRES_OFF + (size_t)(st*344 + 343)*4096 + r] = f2bf(last_w[st*4096 + o*64 + c]);
    } else if (d < n_fw + n_lw + n_p1){
      int e = d - n_fw - n_lw; ws[P1_OFF + e] = f2bf(pfc1_w[e]);
    } else {
      int e = d - n_fw - n_lw - n_p1;
      int row = e >> 8, k = e & 255;
      ws[P2_OFF + e] = f2bf(row < 1700 ? pfc2_w[row*256 + k] : 0.f);
    }
  }
}

// ======================= tower =======================

// load this wave's 4 A-frags (ks=2kh+{0,1} x mt{0,1}) of one tile (q in shorts)
#define LOADW(W, q) { \
  W[0] = *(const bf16x8*)(q); \
  W[1] = *(const bf16x8*)((q) + 512); \
  W[2] = *(const bf16x8*)((q) + 1024); \
  W[3] = *(const bf16x8*)((q) + 1536); }

// one conv tap for K-slice kh: 4 ds_read_b64 + 4 MFMA (dy,dx compile-time)
#define TAPB(W, dyc, dxc) { \
  bool v_ = ((unsigned)(py + (dyc) - 3) < 8u) && ((unsigned)(px + (dxc) - 3) < 8u); \
  int pp_ = p + ((dyc) - 3)*8 + ((dxc) - 3); \
  int b_ = (v_ ? rbase + pp_*RS : SM_Z) + khb; \
  bf16x4 l0 = *(const bf16x4*)(sm + b_); \
  bf16x4 h0 = *(const bf16x4*)(sm + b_ + 8); \
  bf16x4 l1 = *(const bf16x4*)(sm + b_ + 32); \
  bf16x4 h1 = *(const bf16x4*)(sm + b_ + 40); \
  bf16x8 B0 = __builtin_shufflevector(l0, h0, 0,1,2,3,4,5,6,7); \
  bf16x8 B1 = __builtin_shufflevector(l1, h1, 0,1,2,3,4,5,6,7); \
  c0 = MFMA32(W[0], B0, c0); \
  c1 = MFMA32(W[1], B0, c1); \
  c0 = MFMA32(W[2], B1, c0); \
  c1 = MFMA32(W[3], B1, c1); }

#define LBAR() { asm volatile("s_waitcnt lgkmcnt(0)" ::: "memory"); \
                 __builtin_amdgcn_s_barrier(); \
                 asm volatile("" ::: "memory"); }

// exchange partial accs between kh pair; returns the full acc this wave keeps
DEV f32x16 kh_exchange(unsigned char* sm, int wave, int lane, int kh,
                       const f32x16& c0, const f32x16& c1){
  float4v* sl = (float4v*)(sm + EXCH + wave*4096) + lane;   // chunk-major, lane*16B
  f32x16 gv = kh ? c0 : c1;
  sl[0]   = float4v{gv[0],gv[1],gv[2],gv[3]};
  sl[64]  = float4v{gv[4],gv[5],gv[6],gv[7]};
  sl[128] = float4v{gv[8],gv[9],gv[10],gv[11]};
  sl[192] = float4v{gv[12],gv[13],gv[14],gv[15]};
  LBAR();
  const float4v* pl = (const float4v*)(sm + EXCH + (wave^4)*4096) + lane;
  float4v q0 = pl[0], q1 = pl[64], q2 = pl[128], q3 = pl[192];
  f32x16 kp = kh ? c1 : c0;
  kp[0]+=q0[0];  kp[1]+=q0[1];  kp[2]+=q0[2];  kp[3]+=q0[3];
  kp[4]+=q1[0];  kp[5]+=q1[1];  kp[6]+=q1[2];  kp[7]+=q1[3];
  kp[8]+=q2[0];  kp[9]+=q2[1];  kp[10]+=q2[2]; kp[11]+=q2[3];
  kp[12]+=q3[0]; kp[13]+=q3[1]; kp[14]+=q3[2]; kp[15]+=q3[3];
  return kp;
}

DEV void conv_epi(const f32x16& acc, int kh, int p, int wb, int hi,
                  unsigned char* smp, const float* sp, const float* bp){
  int rowb = wb + p*RS + kh*64 + hi*8;
  #pragma unroll
  for (int rg = 0; rg < 4; ++rg){
    int o0 = kh*32 + rg*8 + hi*4;
    unsigned short bb[4];
    #pragma unroll
    for (int e = 0; e < 4; ++e){
      float v = sp[o0+e]*acc[rg*4+e] + bp[o0+e];
      v = v > 0.f ? v : 0.f;
      bb[e] = f2bf(v);
    }
    *(ushort4v*)(smp + rowb + rg*16) = ushort4v{bb[0],bb[1],bb[2],bb[3]};
  }
}

DEV void res_epi(const f32x16& acc, u32x8& res, int kh, int p, int wb, int hi,
                 unsigned char* smp, const float* lsp, const float* lbp){
  int rowb = wb + p*RS + kh*64 + hi*8;
  #pragma unroll
  for (int rg = 0; rg < 4; ++rg){
    int o0 = kh*32 + rg*8 + hi*4;
    unsigned short bb[4];
    #pragma unroll
    for (int e = 0; e < 4; ++e){
      unsigned pr = res[rg*2 + (e>>1)];
      float rv = bf2f((unsigned short)((e & 1) ? (pr >> 16) : (pr & 0xffffu)));
      float v = lsp[o0+e]*acc[rg*4+e] + lbp[o0+e] + rv;
      v = v > 0.f ? v : 0.f;
      bb[e] = f2bf(v);
    }
    res[rg*2]   = (unsigned)bb[0] | ((unsigned)bb[1] << 16);
    res[rg*2+1] = (unsigned)bb[2] | ((unsigned)bb[3] << 16);
    *(ushort4v*)(smp + rowb + rg*16) = ushort4v{bb[0],bb[1],bb[2],bb[3]};
  }
}

DEV void first_epi(const f32x16& acc, u32x8& res, int kh, int p, float idsv,
                   int img, int wb, int hi, unsigned char* smp,
                   const float* fsp, const float* fbp, unsigned short* act0){
  int rowb = wb + p*RS + kh*64 + hi*8;
  #pragma unroll
  for (int rg = 0; rg < 4; ++rg){
    int o0 = kh*32 + rg*8 + hi*4;
    unsigned short bb[4];
    #pragma unroll
    for (int e = 0; e < 4; ++e){
      int o = o0 + e;
      int oc = o < 63 ? o : 62;          // avoid OOB load of 63-entry arrays
      float v = fsp[oc]*acc[rg*4+e] + fbp[oc];
      v = v > 0.f ? v : 0.f;
      if (o == 63) v = idsv;             // ids channel, no bn/relu
      bb[e] = f2bf(v);
    }
    res[rg*2]   = (unsigned)bb[0] | ((unsigned)bb[1] << 16);
    res[rg*2+1] = (unsigned)bb[2] | ((unsigned)bb[3] << 16);
    *(ushort4v*)(smp + rowb + rg*16) = ushort4v{bb[0],bb[1],bb[2],bb[3]};
    *(ushort4v*)(act0 + (size_t)img*4096 + p*64 + o0) = ushort4v{bb[0],bb[1],bb[2],bb[3]};
  }
}

__global__ __launch_bounds__(1024, 4) void tower_k(
    const float* __restrict__ x,
    const float* __restrict__ first_s, const float* __restrict__ first_b,
    const float* __restrict__ res_s,   const float* __restrict__ res_b,
    const float* __restrict__ last_s,  const float* __restrict__ last_b,
    const float* __restrict__ vconv_w, const float* __restrict__ v_s, const float* __restrict__ v_b,
    const float* __restrict__ vfc1_w,  const float* __restrict__ vfc1_b,
    const float* __restrict__ vfc2_w,  const float* __restrict__ vfc2_b,
    const unsigned short* __restrict__ ws_r, unsigned short* __restrict__ act0,
    float* __restrict__ value_out)
{
  __shared__ unsigned char sm[SM_BYTES];
  int tid = threadIdx.x, lane = tid & 63, wave = tid >> 6;
  int imgi = wave & 3, kh = (wave >> 2) & 1, pg = wave >> 3;
  int img = blockIdx.x * 4 + imgi;

  for (int i = tid*16; i < SM_BYTES; i += 1024*16) *(float4v*)(sm + i) = float4v{0,0,0,0};
  __syncthreads();

  int col = lane & 31, hi = lane >> 5;
  int hi16 = hi << 4;
  int khb = kh*64 + hi16;             // byte offset of this wave's K-slice in an act row
  int p  = pg*32 + col;               // my position (0..63)
  int py = p >> 3, px = p & 7;

  // ---- stage x into padded xin (bf16, overlays ACT_B), channels 0..11 ----
  const float* xim = x + (size_t)img * 832;
  int xinbase = ACT_B + imgi * 3584;
  if (wave < 4){
    int q = (lane >> 3)*14 + (lane & 7) + 3;
    for (int c = 0; c < 12; ++c)
      *(unsigned short*)(sm + xinbase + q*32 + c*2) = f2bf(xim[c*64 + lane]);
  }
  float idsv = xim[768 + p];
  __syncthreads();

  // ---- first conv (K=16, no K-split): wave computes (pg positions, mt=kh) ----
  f32x16 f0 = {};
  const unsigned short* fw = ws_r + FW_OFF;
  int qbx = py*14 + px;
  #pragma unroll
  for (int dy = 0; dy < 7; ++dy){
    bool vy = (unsigned)(py + dy - 3) < 8u;
    int tq = (dy-3)*14;
    #pragma unroll
    for (int dx = 0; dx < 7; ++dx){
      int t = dy*7 + dx;
      bf16x8 a = *(const bf16x8*)(fw + t*1024 + kh*512 + lane*8);
      int q0 = qbx + tq + dx;
      int ba = vy ? (xinbase + q0*32 + hi16) : SM_Z;
      f0 = MFMA32(a, *(const bf16x8*)(sm + ba), f0);
    }
  }
  u32x8 res0;
  first_epi(f0, res0, kh, p, idsv, img, ACT_A + imgi*IMG_ACT, hi, sm,
            first_s, first_b, act0);
  LBAR();

  // ---- residual tower: K-split (kh) waves, A global->VGPR, B 2xb64 from acts ----
  int rbase = ACT_A + imgi*IMG_ACT;
  int wbase = ACT_B + imgi*IMG_ACT;
  const unsigned short* gw = ws_r + WRES_OFF + kh*2048 + lane*8;

  for (int st = 0; st < 7; ++st){
    for (int j = 0; j < 7; ++j){
      int L = st*7 + j;
      f32x16 c0 = {}, c1 = {};
      bf16x8 wA[4], wB[4];
      LOADW(wA, gw);
      #pragma unroll
      for (int t = 0; t < 49; ++t){
        const int dy = t / 7, dx = t % 7;
        if ((t & 1) == 0){
          if (t + 1 < 49) LOADW(wB, gw + (t+1)*4096);
          TAPB(wA, dy, dx);
        } else {
          if (t + 1 < 49) LOADW(wA, gw + (t+1)*4096);
          TAPB(wB, dy, dx);
        }
      }
      gw += 49*4096;
      f32x16 kp = kh_exchange(sm, wave, lane, kh, c0, c1);
      conv_epi(kp, kh, p, wbase, hi, sm, res_s + L*64, res_b + L*64);
      LBAR();
      int tmpb = rbase; rbase = wbase; wbase = tmpb;
    }
    // 1x1 (last_w) + bn + residual + relu
    {
      bf16x8 wA[4];
      LOADW(wA, gw); gw += 4096;
      f32x16 c0 = {}, c1 = {};
      int b = rbase + p*RS + khb;
      bf16x4 l0 = *(const bf16x4*)(sm + b);
      bf16x4 h0 = *(const bf16x4*)(sm + b + 8);
      bf16x4 l1 = *(const bf16x4*)(sm + b + 32);
      bf16x4 h1 = *(const bf16x4*)(sm + b + 40);
      bf16x8 B0 = __builtin_shufflevector(l0, h0, 0,1,2,3,4,5,6,7);
      bf16x8 B1 = __builtin_shufflevector(l1, h1, 0,1,2,3,4,5,6,7);
      c0 = MFMA32(wA[0], B0, c0);
      c1 = MFMA32(wA[1], B0, c1);
      c0 = MFMA32(wA[2], B1, c0);
      c1 = MFMA32(wA[3], B1, c1);
      f32x16 kp = kh_exchange(sm, wave, lane, kh, c0, c1);
      res_epi(kp, res0, kh, p, wbase, hi, sm, last_s + st*64, last_b + st*64);
      LBAR();
      int tmpb = rbase; rbase = wbase; wbase = tmpb;
    }
  }

  // ---- value head ----
  float part = 0.f;
  #pragma unroll
  for (int rg = 0; rg < 4; ++rg){
    #pragma unroll
    for (int eh = 0; eh < 2; ++eh){
      unsigned pr = res0[rg*2+eh];
      int ob = kh*32 + rg*8 + hi*4 + eh*2;
      part += bf2f((unsigned short)(pr & 0xffffu))*vconv_w[ob]
            + bf2f((unsigned short)(pr >> 16))*vconv_w[ob+1];
    }
  }
  part += __shfl_xor(part, 32);
  float* vpf = (float*)(sm + EXCH);            // [imgi][kh][64 pos] (EXCH dead now)
  if (lane < 32) vpf[(imgi*2 + kh)*64 + pg*32 + lane] = part;
  __syncthreads();

  if (wave < 4){                               // wave w finishes image imgi==w
    int mimg = blockIdx.x*4 + wave;
    float vs = v_s[0], vb = v_b[0];
    float sum = vpf[(wave*2)*64 + lane] + vpf[(wave*2 + 1)*64 + lane];
    float vv = vs*sum + vb; vv = vv > 0.f ? vv : 0.f;
    float* vbuf = (float*)(sm + EXCH + 2048) + wave*64;
    vbuf[lane] = vv;
    asm volatile("s_waitcnt lgkmcnt(0)" ::: "memory");
    float hidv[4];
    #pragma unroll
    for (int it = 0; it < 4; ++it){
      int jj = it*64 + lane;
      float a = vfc1_b[jj];
      for (int k = 0; k < 64; k += 4){
        float4v vv4 = *(const float4v*)(vbuf + k);
        a += vfc1_w[jj*64+k]*vv4[0] + vfc1_w[jj*64+k+1]*vv4[1]
           + vfc1_w[jj*64+k+2]*vv4[2] + vfc1_w[jj*64+k+3]*vv4[3];
      }
      hidv[it] = a > 0.f ? a : 0.f;
    }
    float tot = 0.f;
    #pragma unroll
    for (int it = 0; it < 4; ++it) tot += hidv[it]*vfc2_w[it*64 + lane];
    #pragma unroll
    for (int off = 32; off; off >>= 1) tot += __shfl_xor(tot, off);
    if (lane == 0) value_out[mimg] = tanhf(tot + vfc2_b[0]);
  }
}

// ======================= gather / piece head =======================
__global__ __launch_bounds__(256) void gather_k(const unsigned short* __restrict__ act0,
                                                unsigned short* __restrict__ pvec,
                                                float* __restrict__ pid_out){
  int lane = threadIdx.x & 63, wave = threadIdx.x >> 6;
  int img = blockIdx.x*4 + wave;
  const unsigned short* arow = act0 + (size_t)img*4096;
  int myid = (int)bf2f(arow[lane*64 + 63]);
  int mypos = 0, mypres = 0;
  for (int p = 0; p < 32; ++p){
    unsigned long long m = __ballot(myid == (p+1));
    if (lane == p){ mypres = (m != 0ull); mypos = mypres ? (__ffsll(m) - 1) : 0; }
  }
  if (lane < 32){
    float v = mypres ? (float)(lane+1) : 0.f;
    #pragma unroll
    for (int s = 0; s < 8; ++s) pid_out[(size_t)img*256 + s*32 + lane] = v;
  }
  for (int p = 0; p < 32; ++p){
    int q  = __shfl(mypos, p);
    int pr = __shfl(mypres, p);
    unsigned short v = pr ? arow[q*64 + lane] : (unsigned short)0;
    pvec[(size_t)img*2048 + p*64 + lane] = v;
  }
}

// ======================= policy head GEMMs =======================
__global__ __launch_bounds__(256) void fc1_k(const unsigned short* __restrict__ pvec,
                                             const unsigned short* __restrict__ w,
                                             const float* __restrict__ bias,
                                             unsigned short* __restrict__ hid){
  int lane = threadIdx.x & 63, wave = threadIdx.x >> 6;
  int col = lane & 31, hi = lane >> 5;
  int wm = wave >> 1, wn = wave & 1;
  int m0 = blockIdx.x*128 + wm*64;
  int n0 = blockIdx.y*128 + wn*64;
  f32x16 a00 = {}, a01 = {}, a10 = {}, a11 = {};
  for (int k = 0; k < 2048; k += 16){
    bf16x8 A0 = *(const bf16x8*)(pvec + (size_t)(m0+col)*2048    + k + hi*8);
    bf16x8 A1 = *(const bf16x8*)(pvec + (size_t)(m0+32+col)*2048 + k + hi*8);
    bf16x8 B0 = *(const bf16x8*)(w + (size_t)(n0+col)*2048    + k + hi*8);
    bf16x8 B1 = *(const bf16x8*)(w + (size_t)(n0+32+col)*2048 + k + hi*8);
    a00 = MFMA32(A0, B0, a00); a01 = MFMA32(A0, B1, a01);
    a10 = MFMA32(A1, B0, a10); a11 = MFMA32(A1, B1, a11);
  }
  #pragma unroll
  for (int mt = 0; mt < 2; ++mt)
    #pragma unroll
    for (int nt = 0; nt < 2; ++nt){
      const f32x16& acc = mt == 0 ? (nt == 0 ? a00 : a01) : (nt == 0 ? a10 : a11);
      int jcol = n0 + nt*32 + col;
      float bj = bias[jcol];
      #pragma unroll
      for (int rg = 0; rg < 4; ++rg)
        #pragma unroll
        for (int e = 0; e < 4; ++e){
          int n = m0 + mt*32 + rg*8 + hi*4 + e;
          float v = acc[rg*4+e] + bj; v = v > 0.f ? v : 0.f;
          hid[(size_t)n*256 + jcol] = f2bf(v);
        }
    }
}

__global__ __launch_bounds__(256) void fc2_k(const unsigned short* __restrict__ hid,
                                             const unsigned short* __restrict__ w,
                                             const float* __restrict__ bias,
                                             float* __restrict__ pol){
  int lane = threadIdx.x & 63, wave = threadIdx.x >> 6;
  int col = lane & 31, hi = lane >> 5;
  int wm = wave >> 1, wn = wave & 1;
  int m0 = blockIdx.x*128 + wm*64;
  int n0 = blockIdx.y*128 + wn*64;
  f32x16 a00 = {}, a01 = {}, a10 = {}, a11 = {};
  for (int k = 0; k < 256; k += 16){
    bf16x8 A0 = *(const bf16x8*)(hid + (size_t)(m0+col)*256    + k + hi*8);
    bf16x8 A1 = *(const bf16x8*)(hid + (size_t)(m0+32+col)*256 + k + hi*8);
    bf16x8 B0 = *(const bf16x8*)(w + (size_t)(n0+col)*256    + k + hi*8);
    bf16x8 B1 = *(const bf16x8*)(w + (size_t)(n0+32+col)*256 + k + hi*8);
    a00 = MFMA32(A0, B0, a00); a01 = MFMA32(A0, B1, a01);
    a10 = MFMA32(A1, B0, a10); a11 = MFMA32(A1, B1, a11);
  }
  #pragma unroll
  for (int mt = 0; mt < 2; ++mt)
    #pragma unroll
    for (int nt = 0; nt < 2; ++nt){
      const f32x16& acc = mt == 0 ? (nt == 0 ? a00 : a01) : (nt == 0 ? a10 : a11);
      int jcol = n0 + nt*32 + col;
      if (jcol < 1700){
        float bj = bias[jcol];
        #pragma unroll
        for (int rg = 0; rg < 4; ++rg)
          #pragma unroll
          for (int e = 0; e < 4; ++e){
            int n = m0 + mt*32 + rg*8 + hi*4 + e;
            pol[(size_t)n*1700 + jcol] = acc[rg*4+e] + bj;
          }
      }
    }
}

// ======================= launch =======================
extern "C" void kernel_launch(void* const* d_in, const int* in_sizes, int n_in,
                              void* d_out, int out_size, void* d_ws, size_t ws_size,
                              hipStream_t stream){
  const float* x       = (const float*)d_in[0];
  const float* first_w = (const float*)d_in[1];
  const float* first_s = (const float*)d_in[2];
  const float* first_b = (const float*)d_in[3];
  const float* res_w   = (const float*)d_in[4];
  const float* res_s   = (const float*)d_in[5];
  const float* res_b   = (const float*)d_in[6];
  const float* last_w  = (const float*)d_in[7];
  const float* last_s  = (const float*)d_in[8];
  const float* last_b  = (const float*)d_in[9];
  const float* pfc1_w  = (const float*)d_in[10];
  const float* pfc1_b  = (const float*)d_in[11];
  const float* pfc2_w  = (const float*)d_in[12];
  const float* pfc2_b  = (const float*)d_in[13];
  const float* vconv_w = (const float*)d_in[14];
  const float* v_s     = (const float*)d_in[15];
  const float* v_b     = (const float*)d_in[16];
  const float* vfc1_w  = (const float*)d_in[17];
  const float* vfc1_b  = (const float*)d_in[18];
  const float* vfc2_w  = (const float*)d_in[19];
  const float* vfc2_b  = (const float*)d_in[20];
  unsigned short* ws = (unsigned short*)d_ws;
  float* out = (float*)d_out;

  prep_res_k <<<3136, 256, 0, stream>>>(res_w, ws);
  prep_misc_k<<<1024, 256, 0, stream>>>(first_w, last_w, pfc1_w, pfc2_w, ws);
  tower_k    <<<256, 1024, 0, stream>>>(x, first_s, first_b, res_s, res_b, last_s, last_b,
                                        vconv_w, v_s, v_b, vfc1_w, vfc1_b, vfc2_w, vfc2_b,
                                        ws, ws + ACT0_OFF, out + VAL_OFF);
  gather_k   <<<256, 256, 0, stream>>>(ws + ACT0_OFF, ws + PV_OFF, out + PID_OFF);
  fc1_k      <<<dim3(8, 2), 256, 0, stream>>>(ws + PV_OFF, ws + P1_OFF, pfc1_b, ws + HID_OFF);
  fc2_k      <<<dim3(8, 14), 256, 0, stream>>>(ws + HID_OFF, ws + P2_OFF, pfc2_b, out);
}